// Round 1
// baseline (1193.241 us; speedup 1.0000x reference)
//
#include <hip/hip_runtime.h>

// Correlation cost volume, specialized: B=16, C=256, H=W=96, k=1, d=4, s1=s2=1.
// out[b, (dy+4)*9+(dx+4), y, x] = (1/256) * sum_c x1[b,c,y,x] * x2[b,c,y+dy,x+dx]
// (x2 zero-padded by 4). Thread owns (8-pixel x-strip, one dy, all 9 dx) -> 72 accs.
// Block = 4 rows x 9 dy x 12 strips = 432 threads; grid = 24 row-tiles x 16 batch.
//
// v2: chunked LDS layout (8 payload floats + 4 pad, pitch 12) for BOTH tiles.
//  - x2 window read becomes 4x ds_read_b128 (was 2xb128 + 16x ds_read_b32)
//  - 16B-block index has +3s term (odd stride) -> spreads 12 strips over all
//    8 bank groups, max 2-way conflict (free). Old layout: 5.86e7 conflict cyc.
//  - x2 staging stores become float4 (were scalar at pitch 105).

namespace {
constexpr int Bsz = 16, Cch = 256, Hh = 96, Ww = 96;
constexpr int Dd = 4, NDisp = 9;            // 2*d+1
constexpr int TH = 4;                       // output rows per block
constexpr int PX = 8;                       // pixels per thread (x)
constexpr int NSTRIP = Ww / PX;             // 12
constexpr int CC = 4;                       // channels per LDS stage
constexpr int X2ROWS = TH + 2 * Dd;         // 12
constexpr int NT = TH * NDisp * NSTRIP;     // 432 threads
constexpr int HW = Hh * Ww;                 // 9216

// chunked layout: 8 payload floats + 4 pad per chunk
constexpr int CHUNK = 12;                   // floats per chunk slot
constexpr int X1CH  = Ww / 8;               // 12 chunks per x1 row
constexpr int X1RP  = X1CH * CHUNK;         // 144 floats per x1 row
constexpr int X1_LDS = CC * TH * X1RP;      // 2304 floats
constexpr int X2COLS = 104;                 // padded cols stored (need 0..103)
constexpr int X2CH  = X2COLS / 8;           // 13 chunks per x2 row
constexpr int X2RP  = X2CH * CHUNK;         // 156 floats per x2 row
constexpr int X2_LDS = CC * X2ROWS * X2RP;  // 7488 floats
constexpr int X2_GROUPS = X2COLS / 4;       // 26 float4 groups per padded row
constexpr int X1_F4 = CC * TH * Ww / 4;     // 384 staging items
constexpr int X2_F4 = CC * X2ROWS * X2_GROUPS;  // 1248 items
constexpr int N_ITEMS = X1_F4 + X2_F4;      // 1632 -> <=4 per thread
}

__global__ __launch_bounds__(NT, 4)
void corr81(const float* __restrict__ x1, const float* __restrict__ x2,
            float* __restrict__ out) {
  __shared__ float lds[X1_LDS + X2_LDS + 4];  // +4 = dummy f4 slot for pad items

  const int t = threadIdx.x;
  const int y0 = blockIdx.x * TH;
  const int b  = blockIdx.y;

  const int r   = t / (NDisp * NSTRIP);   // 0..3  output row within tile
  const int rem = t % (NDisp * NSTRIP);
  const int dyi = rem / NSTRIP;           // 0..8  (dy+4)
  const int s   = rem % NSTRIP;           // 0..11 strip
  const int x0  = s * PX;

  const float* __restrict__ x1b = x1 + (size_t)b * Cch * HW;
  const float* __restrict__ x2b = x2 + (size_t)b * Cch * HW;

  // ---- precompute staging descriptors (constant 4 slots, mask invalid) ----
  const float* gp[4];
  int  loff[4];
  bool zero[4];
#pragma unroll
  for (int j = 0; j < 4; ++j) {
    int i = t + j * NT;
    if (i >= N_ITEMS) {                     // pad slot: write to dummy LDS tail
      gp[j] = x1b; loff[j] = X1_LDS + X2_LDS; zero[j] = true;
    } else if (i < X1_F4) {
      int c    = i / (TH * Ww / 4);         // 96 f4 per channel (4 rows)
      int q    = i % (TH * Ww / 4);
      int grow = q / (Ww / 4);              // 0..3 row in tile
      int col  = (q % (Ww / 4)) * 4;        // 0,4,...,92
      gp[j]   = x1b + c * HW + (size_t)(y0 + grow) * Ww + col;
      loff[j] = c * (TH * X1RP) + grow * X1RP + (col >> 3) * CHUNK + (col & 7);
      zero[j] = false;
    } else {
      int m  = i - X1_F4;
      int c  = m / (X2ROWS * X2_GROUPS);
      int m2 = m % (X2ROWS * X2_GROUPS);
      int ry = m2 / X2_GROUPS;              // 0..11 padded row
      int g  = m2 % X2_GROUPS;              // col group: padded cols [4g,4g+3]
      int pc = g * 4;
      int gy = y0 + ry - Dd;
      bool z = (gy < 0) | (gy >= Hh) | (g == 0) | (g == X2_GROUPS - 1);
      gp[j]   = z ? x2b : (x2b + c * HW + gy * Ww + (pc - 4));
      loff[j] = X1_LDS + c * (X2ROWS * X2RP) + ry * X2RP
              + (pc >> 3) * CHUNK + (pc & 7);
      zero[j] = z;
    }
  }

  float acc[NDisp][PX];
#pragma unroll
  for (int i = 0; i < NDisp; ++i)
#pragma unroll
    for (int j = 0; j < PX; ++j) acc[i][j] = 0.f;

  // per-thread LDS read bases (cc strides folded into ds imm offsets)
  const float* ap0 = lds + r * X1RP + s * CHUNK;
  const float* bp0 = lds + X1_LDS + (r + dyi) * X2RP + s * CHUNK;

  // ---- prefetch stage 0 into registers ----
  float4 v[4];
#pragma unroll
  for (int j = 0; j < 4; ++j)
    v[j] = zero[j] ? make_float4(0.f, 0.f, 0.f, 0.f) : *(const float4*)gp[j];

  for (int c0 = 0; c0 < Cch; c0 += CC) {
    __syncthreads();                        // previous compute done with LDS
    // registers -> LDS, all float4 (chunked layout keeps 16B alignment)
#pragma unroll
    for (int j = 0; j < 4; ++j)
      *(float4*)(lds + loff[j]) = v[j];
    __syncthreads();
    // issue next stage's global loads before compute -> latency overlap
    if (c0 + CC < Cch) {
#pragma unroll
      for (int j = 0; j < 4; ++j) {
        gp[j] += CC * HW;
        v[j] = zero[j] ? make_float4(0.f, 0.f, 0.f, 0.f) : *(const float4*)gp[j];
      }
    }
    // ---- compute: per channel 2 + 4 ds_read_b128, 72 FMAs ----
#pragma unroll
    for (int cc = 0; cc < CC; ++cc) {
      const float* ap = ap0 + cc * (TH * X1RP);
      float a[PX];
      *(float4*)(a)     = *(const float4*)(ap);
      *(float4*)(a + 4) = *(const float4*)(ap + 4);
      const float* bp = bp0 + cc * (X2ROWS * X2RP);
      float bb[PX + 2 * Dd];
      *(float4*)(bb)      = *(const float4*)(bp);           // chunk s   [0..3]
      *(float4*)(bb + 4)  = *(const float4*)(bp + 4);       // chunk s   [4..7]
      *(float4*)(bb + 8)  = *(const float4*)(bp + CHUNK);   // chunk s+1 [0..3]
      *(float4*)(bb + 12) = *(const float4*)(bp + CHUNK + 4); // chunk s+1 [4..7]
#pragma unroll
      for (int dx = 0; dx < NDisp; ++dx)
#pragma unroll
        for (int px = 0; px < PX; ++px)
          acc[dx][px] += a[px] * bb[px + dx];
    }
  }

  // ---- epilogue: 9 channels x 8 contiguous pixels per thread ----
  const float nrm = 1.0f / (float)Cch;
  float* ob = out + ((size_t)b * (NDisp * NDisp) + (size_t)dyi * NDisp) * HW
                  + (size_t)(y0 + r) * Ww + x0;
#pragma unroll
  for (int dx = 0; dx < NDisp; ++dx) {
    float4 w0, w1;
    w0.x = acc[dx][0] * nrm; w0.y = acc[dx][1] * nrm;
    w0.z = acc[dx][2] * nrm; w0.w = acc[dx][3] * nrm;
    w1.x = acc[dx][4] * nrm; w1.y = acc[dx][5] * nrm;
    w1.z = acc[dx][6] * nrm; w1.w = acc[dx][7] * nrm;
    *(float4*)(ob + (size_t)dx * HW)     = w0;
    *(float4*)(ob + (size_t)dx * HW + 4) = w1;
  }
}

extern "C" void kernel_launch(void* const* d_in, const int* in_sizes, int n_in,
                              void* d_out, int out_size, void* d_ws, size_t ws_size,
                              hipStream_t stream) {
  const float* x1 = (const float*)d_in[0];
  const float* x2 = (const float*)d_in[1];
  float* out = (float*)d_out;
  dim3 grid(Hh / TH, Bsz);   // 24 row-tiles x 16 batches = 384 blocks
  dim3 block(NT);            // 432 threads
  hipLaunchKernelGGL(corr81, grid, block, 0, stream, x1, x2, out);
}

// Round 2
// 413.318 us; speedup vs baseline: 2.8870x; 2.8870x over previous
//
#include <hip/hip_runtime.h>

// Correlation cost volume, specialized: B=16, C=256, H=W=96, k=1, d=4, s1=s2=1.
// out[b, (dy+4)*9+(dx+4), y, x] = (1/256) * sum_c x1[b,c,y,x] * x2[b,c,y+dy,x+dx]
// (x2 zero-padded by 4). Thread owns (8-pixel x-strip, one dy, all 9 dx) -> 72 accs.
// Block = 4 rows x 9 dy x 12 strips = 432 threads; grid = 24 row-tiles x 16 batch.
//
// v3 = v2 chunked-LDS layout, launch_bounds reverted to (NT, 2).
//  - (NT,4) in v2 capped VGPR at 64 -> 72-acc array spilled to scratch:
//    WRITE_SIZE 46MB->1.75GB, dur 288->988us. (NT,2) gives ~100 VGPR, no spill.
//  - chunked layout (8 payload + 4 pad floats per 12-float chunk) for BOTH tiles:
//    x2 window = 4x ds_read_b128 (was 2xb128 + 16x ds_read_b32); odd chunk
//    stride spreads strips across bank groups (conflicts 5.86e7 -> 2.3e7).

namespace {
constexpr int Bsz = 16, Cch = 256, Hh = 96, Ww = 96;
constexpr int Dd = 4, NDisp = 9;            // 2*d+1
constexpr int TH = 4;                       // output rows per block
constexpr int PX = 8;                       // pixels per thread (x)
constexpr int NSTRIP = Ww / PX;             // 12
constexpr int CC = 4;                       // channels per LDS stage
constexpr int X2ROWS = TH + 2 * Dd;         // 12
constexpr int NT = TH * NDisp * NSTRIP;     // 432 threads
constexpr int HW = Hh * Ww;                 // 9216

// chunked layout: 8 payload floats + 4 pad per chunk
constexpr int CHUNK = 12;                   // floats per chunk slot
constexpr int X1CH  = Ww / 8;               // 12 chunks per x1 row
constexpr int X1RP  = X1CH * CHUNK;         // 144 floats per x1 row
constexpr int X1_LDS = CC * TH * X1RP;      // 2304 floats
constexpr int X2COLS = 104;                 // padded cols stored (need 0..103)
constexpr int X2CH  = X2COLS / 8;           // 13 chunks per x2 row
constexpr int X2RP  = X2CH * CHUNK;         // 156 floats per x2 row
constexpr int X2_LDS = CC * X2ROWS * X2RP;  // 7488 floats
constexpr int X2_GROUPS = X2COLS / 4;       // 26 float4 groups per padded row
constexpr int X1_F4 = CC * TH * Ww / 4;     // 384 staging items
constexpr int X2_F4 = CC * X2ROWS * X2_GROUPS;  // 1248 items
constexpr int N_ITEMS = X1_F4 + X2_F4;      // 1632 -> <=4 per thread
}

__global__ __launch_bounds__(NT, 2)
void corr81(const float* __restrict__ x1, const float* __restrict__ x2,
            float* __restrict__ out) {
  __shared__ __align__(16) float lds[X1_LDS + X2_LDS + 4];  // +4: dummy f4 slot

  const int t = threadIdx.x;
  const int y0 = blockIdx.x * TH;
  const int b  = blockIdx.y;

  const int r   = t / (NDisp * NSTRIP);   // 0..3  output row within tile
  const int rem = t % (NDisp * NSTRIP);
  const int dyi = rem / NSTRIP;           // 0..8  (dy+4)
  const int s   = rem % NSTRIP;           // 0..11 strip
  const int x0  = s * PX;

  const float* __restrict__ x1b = x1 + (size_t)b * Cch * HW;
  const float* __restrict__ x2b = x2 + (size_t)b * Cch * HW;

  // ---- precompute staging descriptors (constant 4 slots, mask invalid) ----
  const float* gp[4];
  int  loff[4];
  bool zero[4];
#pragma unroll
  for (int j = 0; j < 4; ++j) {
    int i = t + j * NT;
    if (i >= N_ITEMS) {                     // pad slot: write to dummy LDS tail
      gp[j] = x1b; loff[j] = X1_LDS + X2_LDS; zero[j] = true;
    } else if (i < X1_F4) {
      int c    = i / (TH * Ww / 4);         // 96 f4 per channel (4 rows)
      int q    = i % (TH * Ww / 4);
      int grow = q / (Ww / 4);              // 0..3 row in tile
      int col  = (q % (Ww / 4)) * 4;        // 0,4,...,92
      gp[j]   = x1b + c * HW + (size_t)(y0 + grow) * Ww + col;
      loff[j] = c * (TH * X1RP) + grow * X1RP + (col >> 3) * CHUNK + (col & 7);
      zero[j] = false;
    } else {
      int m  = i - X1_F4;
      int c  = m / (X2ROWS * X2_GROUPS);
      int m2 = m % (X2ROWS * X2_GROUPS);
      int ry = m2 / X2_GROUPS;              // 0..11 padded row
      int g  = m2 % X2_GROUPS;              // col group: padded cols [4g,4g+3]
      int pc = g * 4;
      int gy = y0 + ry - Dd;
      bool z = (gy < 0) | (gy >= Hh) | (g == 0) | (g == X2_GROUPS - 1);
      gp[j]   = z ? x2b : (x2b + c * HW + gy * Ww + (pc - 4));
      loff[j] = X1_LDS + c * (X2ROWS * X2RP) + ry * X2RP
              + (pc >> 3) * CHUNK + (pc & 7);
      zero[j] = z;
    }
  }

  float acc[NDisp][PX];
#pragma unroll
  for (int i = 0; i < NDisp; ++i)
#pragma unroll
    for (int j = 0; j < PX; ++j) acc[i][j] = 0.f;

  // per-thread LDS read bases (cc strides folded into ds imm offsets)
  const float* ap0 = lds + r * X1RP + s * CHUNK;
  const float* bp0 = lds + X1_LDS + (r + dyi) * X2RP + s * CHUNK;

  // ---- prefetch stage 0 into registers ----
  float4 v[4];
#pragma unroll
  for (int j = 0; j < 4; ++j)
    v[j] = zero[j] ? make_float4(0.f, 0.f, 0.f, 0.f) : *(const float4*)gp[j];

  for (int c0 = 0; c0 < Cch; c0 += CC) {
    __syncthreads();                        // previous compute done with LDS
    // registers -> LDS, all float4 (chunked layout keeps 16B alignment)
#pragma unroll
    for (int j = 0; j < 4; ++j)
      *(float4*)(lds + loff[j]) = v[j];
    __syncthreads();
    // issue next stage's global loads before compute -> latency overlap
    if (c0 + CC < Cch) {
#pragma unroll
      for (int j = 0; j < 4; ++j) {
        gp[j] += CC * HW;
        v[j] = zero[j] ? make_float4(0.f, 0.f, 0.f, 0.f) : *(const float4*)gp[j];
      }
    }
    // ---- compute: per channel 2 + 4 ds_read_b128, 72 FMAs ----
#pragma unroll
    for (int cc = 0; cc < CC; ++cc) {
      const float* ap = ap0 + cc * (TH * X1RP);
      float a[PX];
      *(float4*)(a)     = *(const float4*)(ap);
      *(float4*)(a + 4) = *(const float4*)(ap + 4);
      const float* bp = bp0 + cc * (X2ROWS * X2RP);
      float bb[PX + 2 * Dd];
      *(float4*)(bb)      = *(const float4*)(bp);             // chunk s   [0..3]
      *(float4*)(bb + 4)  = *(const float4*)(bp + 4);         // chunk s   [4..7]
      *(float4*)(bb + 8)  = *(const float4*)(bp + CHUNK);     // chunk s+1 [0..3]
      *(float4*)(bb + 12) = *(const float4*)(bp + CHUNK + 4); // chunk s+1 [4..7]
#pragma unroll
      for (int dx = 0; dx < NDisp; ++dx)
#pragma unroll
        for (int px = 0; px < PX; ++px)
          acc[dx][px] += a[px] * bb[px + dx];
    }
  }

  // ---- epilogue: 9 channels x 8 contiguous pixels per thread ----
  const float nrm = 1.0f / (float)Cch;
  float* ob = out + ((size_t)b * (NDisp * NDisp) + (size_t)dyi * NDisp) * HW
                  + (size_t)(y0 + r) * Ww + x0;
#pragma unroll
  for (int dx = 0; dx < NDisp; ++dx) {
    float4 w0, w1;
    w0.x = acc[dx][0] * nrm; w0.y = acc[dx][1] * nrm;
    w0.z = acc[dx][2] * nrm; w0.w = acc[dx][3] * nrm;
    w1.x = acc[dx][4] * nrm; w1.y = acc[dx][5] * nrm;
    w1.z = acc[dx][6] * nrm; w1.w = acc[dx][7] * nrm;
    *(float4*)(ob + (size_t)dx * HW)     = w0;
    *(float4*)(ob + (size_t)dx * HW + 4) = w1;
  }
}

extern "C" void kernel_launch(void* const* d_in, const int* in_sizes, int n_in,
                              void* d_out, int out_size, void* d_ws, size_t ws_size,
                              hipStream_t stream) {
  const float* x1 = (const float*)d_in[0];
  const float* x2 = (const float*)d_in[1];
  float* out = (float*)d_out;
  dim3 grid(Hh / TH, Bsz);   // 24 row-tiles x 16 batches = 384 blocks
  dim3 block(NT);            // 432 threads
  hipLaunchKernelGGL(corr81, grid, block, 0, stream, x1, x2, out);
}